// Round 8
// baseline (533.398 us; speedup 1.0000x reference)
//
#include <hip/hip_runtime.h>
#include <hip/hip_bf16.h>
#include <stdint.h>

#define DEVFN static __device__ __forceinline__

typedef __bf16 bf16x8 __attribute__((ext_vector_type(8)));
typedef float f32x4 __attribute__((ext_vector_type(4)));
typedef float f32x16 __attribute__((ext_vector_type(16)));

DEVFN unsigned short f2bf(float f) {
  unsigned int u = __float_as_uint(f);
  u += 0x7FFFu + ((u >> 16) & 1u);
  return (unsigned short)(u >> 16);
}

DEVFN float softplus_f(float s) {
  return fmaxf(s, 0.0f) + log1pf(__expf(-fabsf(s)));
}

DEVFN void load_lds16(const void* g, void* l) {
  __builtin_amdgcn_global_load_lds(
      (const __attribute__((address_space(1))) void*)g,
      (__attribute__((address_space(3))) void*)l, 16, 0, 0);
}

// ---------------- elementwise: A = mW + softplus(sW)*zW  (fp32 -> bf16) ----
__global__ void fuse_w_kernel(const float* __restrict__ m, const float* __restrict__ s,
                              const float* __restrict__ z, unsigned short* __restrict__ o,
                              int n4) {
  int stride = gridDim.x * blockDim.x;
  for (int i = blockIdx.x * blockDim.x + threadIdx.x; i < n4; i += stride) {
    float4 mv = reinterpret_cast<const float4*>(m)[i];
    float4 sv = reinterpret_cast<const float4*>(s)[i];
    float4 zv = reinterpret_cast<const float4*>(z)[i];
    ushort4 ov;
    ov.x = f2bf(fmaf(softplus_f(sv.x), zv.x, mv.x));
    ov.y = f2bf(fmaf(softplus_f(sv.y), zv.y, mv.y));
    ov.z = f2bf(fmaf(softplus_f(sv.z), zv.z, mv.z));
    ov.w = f2bf(fmaf(softplus_f(sv.w), zv.w, mv.w));
    reinterpret_cast<ushort4*>(o)[i] = ov;
  }
}

// ---------------- all three biases in one launch ---------------------------
__global__ void bias_all_kernel(const float* __restrict__ mb0, const float* __restrict__ sb0,
                                const float* __restrict__ zb0,
                                const float* __restrict__ mb1, const float* __restrict__ sb1,
                                const float* __restrict__ zb1,
                                const float* __restrict__ mb2, const float* __restrict__ sb2,
                                const float* __restrict__ zb2,
                                float* __restrict__ b0, float* __restrict__ b1,
                                float* __restrict__ b2) {
  int i = blockIdx.x * blockDim.x + threadIdx.x;
  if (i < 4096) {
    b0[i] = fmaf(softplus_f(sb0[i]), zb0[i], mb0[i]);
  } else if (i < 8192) {
    int k = i - 4096;
    b1[k] = fmaf(softplus_f(sb1[k]), zb1[k], mb1[k]);
  } else if (i < 9216) {
    int k = i - 8192;
    b2[k] = fmaf(softplus_f(sb2[k]), zb2[k], mb2[k]);
  }
}

// ---------------- x fp32 -> bf16 -------------------------------------------
__global__ void xconv_kernel(const float* __restrict__ x, unsigned short* __restrict__ o,
                             int n4) {
  int stride = gridDim.x * blockDim.x;
  for (int i = blockIdx.x * blockDim.x + threadIdx.x; i < n4; i += stride) {
    float4 v = reinterpret_cast<const float4*>(x)[i];
    ushort4 ov;
    ov.x = f2bf(v.x); ov.y = f2bf(v.y); ov.z = f2bf(v.z); ov.w = f2bf(v.w);
    reinterpret_cast<ushort4*>(o)[i] = ov;
  }
}

// ===========================================================================
// Pipelined GEMM, BM=256, BK=32, BN = WN*64; 32x32x16 MFMA (R8).
// 8 waves as (8/WN) M-rows x WN N-cols; wave tile = (32*WN) x 64 =
// FM x 2 fragments of 32x32. Per 32-K tile: 2 k-steps (16k each).
//
// Fragment layouts (verified m74/m101 mapping):
//   A: row = lane&31, k = (lane>>5)*8 + j   (bf16x8, 4 VGPR)
//   B: col = lane&31, k = (lane>>5)*8 + j
//   C/D: col = lane&31, row = (reg&3) + 8*(reg>>2) + 4*(lane>>5), reg 0..15
//
// Pipeline identical to R7 (the verified structure): register double-buffer
// across K-tiles, ring-of-4 LDS slots with stage lead 3 (slots t, t+1, t+2,
// t+3 all distinct), counted vmcnt(LPT) + one barrier per tile, no lgkm
// pins (compiler emits fine-grained counted lgkmcnt for frag->MFMA deps).
//
// T2 swizzle (verified 0 conflicts R4-R7): stage pre-swizzles the per-lane
// GLOBAL source 16B-chunk (cc ^= (row>>1)&3, LDS dest linear); fragment
// reads use chunk (kh+2*ks) ^ ((l31>>1)&3) -- lane-constant, and re-derived
// conflict-free for the 32x32 pattern (8-lane groups cover all 32 banks).
// ===========================================================================
template <int WN, int RELU, int OUTBF16>
__global__ __launch_bounds__(512, 2) void gemm_pipe_kernel(
    const unsigned short* __restrict__ X, const unsigned short* __restrict__ W,
    const float* __restrict__ bias, void* __restrict__ out,
    int M, int N, int K, int gx) {
  constexpr int BN    = WN * 64;          // 256 or 128
  constexpr int FM    = WN;               // A 32-frags per wave (4 or 2)
  constexpr int WaveM = 32 * WN;          // wave M extent (128 or 64)
  constexpr int LPT   = (WN == 4) ? 4 : 3;  // global_load_lds per tile per thread
  constexpr int BS    = BN * 32;          // B slot size, ushorts
  __shared__ __align__(16) unsigned short lds[32768 + 4 * BS];

  // T1: bijective XCD swizzle (grid % 8 == 0 for all launches here)
  const int nwg = gridDim.x;
  const int bid = blockIdx.x;
  const int nid = (bid & 7) * (nwg >> 3) + (bid >> 3);
  const int bx  = nid % gx;
  const int by  = nid / gx;

  const int tid  = threadIdx.x;
  const int lane = tid & 63;
  const int wv   = tid >> 6;                 // 0..7
  const int wm   = wv / WN;
  const int wn   = wv % WN;
  const int row0 = by * 256;
  const int col0 = bx * BN;
  const size_t ldb = (size_t)K * 2;

  // staging: chunk c -> row c>>2, chunkcol c&3; source chunkcol pre-swizzled
  const int cA  = wv * 64 + lane;
  const int rS  = cA >> 2;
  const int ccS = (cA & 3) ^ ((rS >> 1) & 3);
  const char* srcA = (const char*)X + (size_t)(row0 + rS) * ldb + ccS * 16;
  const char* srcB = (const char*)W + (size_t)(col0 + rS) * ldb + ccS * 16;
  char* ldsb = (char*)lds;

  auto stageA = [&](int tt) {
    char* d = ldsb + (tt & 3) * 16384 + wv * 1024;
    const char* s = srcA + (size_t)tt * 64;
    load_lds16(s, d);
    load_lds16(s + 128 * ldb, d + 8192);     // rows +128: swizzle invariant
  };
  auto stageB = [&](int tt) {
    char* d = ldsb + 65536 + (tt & 3) * (BS * 2) + wv * 1024;
    const char* s = srcB + (size_t)tt * 64;
    load_lds16(s, d);
    if constexpr (WN == 4) load_lds16(s + 128 * ldb, d + 8192);
  };

  // fragment byte offsets within a slot (32x32x16 layout + T2 swizzle)
  const int l31 = lane & 31;
  const int kh  = lane >> 5;                 // k-half selector
  const int sw  = (l31 >> 1) & 3;            // T2 swizzle, lane-constant
  int aOff[2][FM], bOff[2][2];
#pragma unroll
  for (int ks = 0; ks < 2; ++ks) {
#pragma unroll
    for (int i = 0; i < FM; ++i)
      aOff[ks][i] = (wm * WaveM + i * 32 + l31) * 64 + (((kh + 2 * ks) ^ sw) * 16);
#pragma unroll
    for (int j = 0; j < 2; ++j)
      bOff[ks][j] = (wn * 64 + j * 32 + l31) * 64 + (((kh + 2 * ks) ^ sw) * 16);
  }

  f32x16 acc[FM][2];
#pragma unroll
  for (int i = 0; i < FM; ++i)
#pragma unroll
    for (int j = 0; j < 2; ++j)
      acc[i][j] = (f32x16)(0.f);

  auto readFrags = [&](int tt, bf16x8 (&aF)[2][FM], bf16x8 (&bF)[2][2]) {
    const char* sa = ldsb + (tt & 3) * 16384;
    const char* sb = ldsb + 65536 + (tt & 3) * (BS * 2);
#pragma unroll
    for (int ks = 0; ks < 2; ++ks) {
#pragma unroll
      for (int i = 0; i < FM; ++i) aF[ks][i] = *(const bf16x8*)(sa + aOff[ks][i]);
#pragma unroll
      for (int j = 0; j < 2; ++j)  bF[ks][j] = *(const bf16x8*)(sb + bOff[ks][j]);
    }
  };
  auto mfmaTile = [&](bf16x8 (&aF)[2][FM], bf16x8 (&bF)[2][2]) {
    __builtin_amdgcn_s_setprio(1);
#pragma unroll
    for (int ks = 0; ks < 2; ++ks)
#pragma unroll
      for (int i = 0; i < FM; ++i)
#pragma unroll
        for (int j = 0; j < 2; ++j)
          acc[i][j] = __builtin_amdgcn_mfma_f32_32x32x16_bf16(
              aF[ks][i], bF[ks][j], acc[i][j], 0, 0, 0);
    __builtin_amdgcn_s_setprio(0);
  };

  const int nt = K >> 5;
  bf16x8 aA[2][FM], bA[2][2], aB[2][FM], bB[2][2];

  // prologue: stage tiles 0,1,2; publish 0,1; preload frags(0)
  stageA(0); stageB(0); stageA(1); stageB(1); stageA(2); stageB(2);
  asm volatile("s_waitcnt vmcnt(%0)" :: "i"(LPT) : "memory");  // t0,t1 landed
  __builtin_amdgcn_s_barrier();
  readFrags(0, aA, bA);

  auto body = [&](int t, bf16x8 (&aCur)[2][FM], bf16x8 (&bCur)[2][2],
                  bf16x8 (&aNxt)[2][FM], bf16x8 (&bNxt)[2][2]) {
    readFrags(t + 1, aNxt, bNxt);
    if (t + 3 < nt) { stageA(t + 3); stageB(t + 3); }
    mfmaTile(aCur, bCur);
    if (t + 3 < nt) asm volatile("s_waitcnt vmcnt(%0)" :: "i"(LPT) : "memory");
    else            asm volatile("s_waitcnt vmcnt(0)" ::: "memory");
    __builtin_amdgcn_s_barrier();  // publish t+2
  };

  for (int t = 0; t < nt - 2; t += 2) {
    body(t,     aA, bA, aB, bB);
    body(t + 1, aB, bB, aA, bA);
  }
  body(nt - 2, aA, bA, aB, bB);   // reads frags(nt-1); drains staging
  mfmaTile(aB, bB);               // compiler inserts the lgkm wait it needs

  // ---- epilogue: bias + optional ReLU; C: col=lane&31,
  // row=(r&3)+8*(r>>2)+4*kh ----
  float bv[2];
#pragma unroll
  for (int j = 0; j < 2; ++j) bv[j] = bias[col0 + wn * 64 + j * 32 + l31];

  const int rb = row0 + wm * WaveM + 4 * kh;
  const int cb = col0 + wn * 64 + l31;
#pragma unroll
  for (int i = 0; i < FM; ++i) {
#pragma unroll
    for (int j = 0; j < 2; ++j) {
#pragma unroll
      for (int r = 0; r < 16; ++r) {
        float v = acc[i][j][r] + bv[j];
        if (RELU) v = fmaxf(v, 0.0f);
        const int row = rb + i * 32 + (r & 3) + 8 * (r >> 2);
        const size_t idx = (size_t)row * N + (cb + j * 32);
        if (OUTBF16) ((unsigned short*)out)[idx] = f2bf(v);
        else         ((float*)out)[idx] = v;
      }
    }
  }
}

// ---------------------------------------------------------------------------
extern "C" void kernel_launch(void* const* d_in, const int* in_sizes, int n_in,
                              void* d_out, int out_size, void* d_ws, size_t ws_size,
                              hipStream_t stream) {
  const float* x   = (const float*)d_in[0];
  const float* mW0 = (const float*)d_in[1];
  const float* sW0 = (const float*)d_in[2];
  const float* zW0 = (const float*)d_in[3];
  const float* mb0 = (const float*)d_in[4];
  const float* sb0 = (const float*)d_in[5];
  const float* zb0 = (const float*)d_in[6];
  const float* mW1 = (const float*)d_in[7];
  const float* sW1 = (const float*)d_in[8];
  const float* zW1 = (const float*)d_in[9];
  const float* mb1 = (const float*)d_in[10];
  const float* sb1 = (const float*)d_in[11];
  const float* zb1 = (const float*)d_in[12];
  const float* mW2 = (const float*)d_in[13];
  const float* sW2 = (const float*)d_in[14];
  const float* zW2 = (const float*)d_in[15];
  const float* mb2 = (const float*)d_in[16];
  const float* sb2 = (const float*)d_in[17];
  const float* zb2 = (const float*)d_in[18];

  char* ws = (char*)d_ws;
  size_t off = 0;
  auto alloc = [&](size_t bytes) {
    char* p = ws + off;
    off += (bytes + 255) & ~(size_t)255;
    return p;
  };
  unsigned short* xb = (unsigned short*)alloc(8192ull * 1024 * 2);
  unsigned short* A0 = (unsigned short*)alloc(4096ull * 1024 * 2);
  unsigned short* A1 = (unsigned short*)alloc(4096ull * 4096 * 2);
  unsigned short* A2 = (unsigned short*)alloc(1024ull * 4096 * 2);
  unsigned short* h1 = (unsigned short*)alloc(8192ull * 4096 * 2);
  unsigned short* h2 = (unsigned short*)alloc(8192ull * 4096 * 2);
  float* b0 = (float*)alloc(4096 * 4);
  float* b1 = (float*)alloc(4096 * 4);
  float* b2 = (float*)alloc(1024 * 4);

  fuse_w_kernel<<<2048, 256, 0, stream>>>(mW0, sW0, zW0, A0, (4096 * 1024) / 4);
  fuse_w_kernel<<<2048, 256, 0, stream>>>(mW1, sW1, zW1, A1, (4096 * 4096) / 4);
  fuse_w_kernel<<<2048, 256, 0, stream>>>(mW2, sW2, zW2, A2, (1024 * 4096) / 4);
  xconv_kernel<<<2048, 256, 0, stream>>>(x, xb, (8192 * 1024) / 4);
  bias_all_kernel<<<36, 256, 0, stream>>>(mb0, sb0, zb0, mb1, sb1, zb1,
                                          mb2, sb2, zb2, b0, b1, b2);

  // layer 0: [8192,1024] @ [4096,1024]^T -> relu -> h1 bf16   (BN=256, 512 wg)
  gemm_pipe_kernel<4, 1, 1><<<512, 512, 0, stream>>>(xb, A0, b0, h1,
                                                     8192, 4096, 1024, 16);
  // layer 1: [8192,4096] @ [4096,4096]^T -> relu -> h2 bf16   (BN=256, 512 wg)
  gemm_pipe_kernel<4, 1, 1><<<512, 512, 0, stream>>>(h1, A1, b1, h2,
                                                     8192, 4096, 4096, 16);
  // layer 2: [8192,4096] @ [1024,4096]^T -> d_out fp32        (BN=128, 256 wg)
  gemm_pipe_kernel<2, 0, 0><<<256, 512, 0, stream>>>(h2, A2, b2, d_out,
                                                     8192, 1024, 4096, 8);
}

// Round 9
// 526.146 us; speedup vs baseline: 1.0138x; 1.0138x over previous
//
#include <hip/hip_runtime.h>
#include <hip/hip_bf16.h>
#include <stdint.h>

#define DEVFN static __device__ __forceinline__

typedef __bf16 bf16x8 __attribute__((ext_vector_type(8)));
typedef float f32x4 __attribute__((ext_vector_type(4)));
typedef float f32x16 __attribute__((ext_vector_type(16)));

DEVFN unsigned short f2bf(float f) {
  unsigned int u = __float_as_uint(f);
  u += 0x7FFFu + ((u >> 16) & 1u);
  return (unsigned short)(u >> 16);
}

DEVFN float softplus_f(float s) {
  return fmaxf(s, 0.0f) + log1pf(__expf(-fabsf(s)));
}

DEVFN void load_lds16(const void* g, void* l) {
  __builtin_amdgcn_global_load_lds(
      (const __attribute__((address_space(1))) void*)g,
      (__attribute__((address_space(3))) void*)l, 16, 0, 0);
}

// ---------------- elementwise: A = mW + softplus(sW)*zW  (fp32 -> bf16) ----
__global__ void fuse_w_kernel(const float* __restrict__ m, const float* __restrict__ s,
                              const float* __restrict__ z, unsigned short* __restrict__ o,
                              int n4) {
  int stride = gridDim.x * blockDim.x;
  for (int i = blockIdx.x * blockDim.x + threadIdx.x; i < n4; i += stride) {
    float4 mv = reinterpret_cast<const float4*>(m)[i];
    float4 sv = reinterpret_cast<const float4*>(s)[i];
    float4 zv = reinterpret_cast<const float4*>(z)[i];
    ushort4 ov;
    ov.x = f2bf(fmaf(softplus_f(sv.x), zv.x, mv.x));
    ov.y = f2bf(fmaf(softplus_f(sv.y), zv.y, mv.y));
    ov.z = f2bf(fmaf(softplus_f(sv.z), zv.z, mv.z));
    ov.w = f2bf(fmaf(softplus_f(sv.w), zv.w, mv.w));
    reinterpret_cast<ushort4*>(o)[i] = ov;
  }
}

// ---------------- all three biases in one launch ---------------------------
__global__ void bias_all_kernel(const float* __restrict__ mb0, const float* __restrict__ sb0,
                                const float* __restrict__ zb0,
                                const float* __restrict__ mb1, const float* __restrict__ sb1,
                                const float* __restrict__ zb1,
                                const float* __restrict__ mb2, const float* __restrict__ sb2,
                                const float* __restrict__ zb2,
                                float* __restrict__ b0, float* __restrict__ b1,
                                float* __restrict__ b2) {
  int i = blockIdx.x * blockDim.x + threadIdx.x;
  if (i < 4096) {
    b0[i] = fmaf(softplus_f(sb0[i]), zb0[i], mb0[i]);
  } else if (i < 8192) {
    int k = i - 4096;
    b1[k] = fmaf(softplus_f(sb1[k]), zb1[k], mb1[k]);
  } else if (i < 9216) {
    int k = i - 8192;
    b2[k] = fmaf(softplus_f(sb2[k]), zb2[k], mb2[k]);
  }
}

// ---------------- x fp32 -> bf16 -------------------------------------------
__global__ void xconv_kernel(const float* __restrict__ x, unsigned short* __restrict__ o,
                             int n4) {
  int stride = gridDim.x * blockDim.x;
  for (int i = blockIdx.x * blockDim.x + threadIdx.x; i < n4; i += stride) {
    float4 v = reinterpret_cast<const float4*>(x)[i];
    ushort4 ov;
    ov.x = f2bf(v.x); ov.y = f2bf(v.y); ov.z = f2bf(v.z); ov.w = f2bf(v.w);
    reinterpret_cast<ushort4*>(o)[i] = ov;
  }
}

// ===========================================================================
// Pipelined GEMM, BM=256, BK=32, BN = WN*64; 32x32x16 MFMA.
// 8 waves as (8/WN) M-rows x WN N-cols; per 32-K tile: 2 k-steps.
//
// R9 swizzle fix: R8's sw=(row>>1)&3 is periodic mod 8, so same-chunk rows
// at stride 8 (lanes 0/8/16/24 of a 32-row fragment read, same kh) aliased
// to one bank-quad -> 4-way conflict (2.5e7 measured, = R2's count).
// New: f(row) = ((row>>1) ^ (row>>3)) & 3 -- aperiodic over rows mod 32.
// Checked: consecutive-8 groups (rows r..r+7 -> all 32 banks), stride-8
// groups (rows {0,8,16,24} -> 4 distinct quads; mixed-kh worst case 2-way
// = free), quad-pair groups -> 2-way. Stage keeps LDS dest linear and
// applies f to the per-lane GLOBAL source chunk (rule 21); rows+128 leaves
// f unchanged (bits 1-4). Read chunk (kh+2ks)^f(l31) is lane-constant.
//
// Fragment layouts (verified m74/m101): A row=lane&31, k=(lane>>5)*8+j;
// C/D col=lane&31, row=(r&3)+8*(r>>2)+4*(lane>>5).
// Pipeline (verified R5-R8): reg double-buffer across tiles, ring-of-4
// slots, stage lead 3, counted vmcnt(LPT) + one barrier per tile, no lgkm
// pins (compiler emits fine-grained counted lgkmcnt for frag->MFMA deps).
// ===========================================================================
template <int WN, int RELU, int OUTBF16>
__global__ __launch_bounds__(512, 2) void gemm_pipe_kernel(
    const unsigned short* __restrict__ X, const unsigned short* __restrict__ W,
    const float* __restrict__ bias, void* __restrict__ out,
    int M, int N, int K, int gx) {
  constexpr int BN    = WN * 64;          // 256 or 128
  constexpr int FM    = WN;               // A 32-frags per wave (4 or 2)
  constexpr int WaveM = 32 * WN;          // wave M extent (128 or 64)
  constexpr int LPT   = (WN == 4) ? 4 : 3;  // global_load_lds per tile per thread
  constexpr int BS    = BN * 32;          // B slot size, ushorts
  __shared__ __align__(16) unsigned short lds[32768 + 4 * BS];

  // T1: bijective XCD swizzle (grid % 8 == 0 for all launches here)
  const int nwg = gridDim.x;
  const int bid = blockIdx.x;
  const int nid = (bid & 7) * (nwg >> 3) + (bid >> 3);
  const int bx  = nid % gx;
  const int by  = nid / gx;

  const int tid  = threadIdx.x;
  const int lane = tid & 63;
  const int wv   = tid >> 6;                 // 0..7
  const int wm   = wv / WN;
  const int wn   = wv % WN;
  const int row0 = by * 256;
  const int col0 = bx * BN;
  const size_t ldb = (size_t)K * 2;

  // staging: chunk c -> row c>>2, chunkcol c&3; source chunkcol pre-swizzled
  // with the aperiodic f(row) = ((row>>1)^(row>>3))&3
  const int cA  = wv * 64 + lane;
  const int rS  = cA >> 2;
  const int ccS = (cA & 3) ^ (((rS >> 1) ^ (rS >> 3)) & 3);
  const char* srcA = (const char*)X + (size_t)(row0 + rS) * ldb + ccS * 16;
  const char* srcB = (const char*)W + (size_t)(col0 + rS) * ldb + ccS * 16;
  char* ldsb = (char*)lds;

  auto stageA = [&](int tt) {
    char* d = ldsb + (tt & 3) * 16384 + wv * 1024;
    const char* s = srcA + (size_t)tt * 64;
    load_lds16(s, d);
    load_lds16(s + 128 * ldb, d + 8192);     // rows +128: f(row) invariant
  };
  auto stageB = [&](int tt) {
    char* d = ldsb + 65536 + (tt & 3) * (BS * 2) + wv * 1024;
    const char* s = srcB + (size_t)tt * 64;
    load_lds16(s, d);
    if constexpr (WN == 4) load_lds16(s + 128 * ldb, d + 8192);
  };

  // fragment byte offsets within a slot (32x32x16 layout + fixed swizzle)
  const int l31 = lane & 31;
  const int kh  = lane >> 5;                 // k-half selector
  const int sw  = ((l31 >> 1) ^ (l31 >> 3)) & 3;  // aperiodic, lane-constant
  int aOff[2][FM], bOff[2][2];
#pragma unroll
  for (int ks = 0; ks < 2; ++ks) {
#pragma unroll
    for (int i = 0; i < FM; ++i)
      aOff[ks][i] = (wm * WaveM + i * 32 + l31) * 64 + (((kh + 2 * ks) ^ sw) * 16);
#pragma unroll
    for (int j = 0; j < 2; ++j)
      bOff[ks][j] = (wn * 64 + j * 32 + l31) * 64 + (((kh + 2 * ks) ^ sw) * 16);
  }

  f32x16 acc[FM][2];
#pragma unroll
  for (int i = 0; i < FM; ++i)
#pragma unroll
    for (int j = 0; j < 2; ++j)
      acc[i][j] = (f32x16)(0.f);

  auto readFrags = [&](int tt, bf16x8 (&aF)[2][FM], bf16x8 (&bF)[2][2]) {
    const char* sa = ldsb + (tt & 3) * 16384;
    const char* sb = ldsb + 65536 + (tt & 3) * (BS * 2);
#pragma unroll
    for (int ks = 0; ks < 2; ++ks) {
#pragma unroll
      for (int i = 0; i < FM; ++i) aF[ks][i] = *(const bf16x8*)(sa + aOff[ks][i]);
#pragma unroll
      for (int j = 0; j < 2; ++j)  bF[ks][j] = *(const bf16x8*)(sb + bOff[ks][j]);
    }
  };
  auto mfmaTile = [&](bf16x8 (&aF)[2][FM], bf16x8 (&bF)[2][2]) {
    __builtin_amdgcn_s_setprio(1);
#pragma unroll
    for (int ks = 0; ks < 2; ++ks)
#pragma unroll
      for (int i = 0; i < FM; ++i)
#pragma unroll
        for (int j = 0; j < 2; ++j)
          acc[i][j] = __builtin_amdgcn_mfma_f32_32x32x16_bf16(
              aF[ks][i], bF[ks][j], acc[i][j], 0, 0, 0);
    __builtin_amdgcn_s_setprio(0);
  };

  const int nt = K >> 5;
  bf16x8 aA[2][FM], bA[2][2], aB[2][FM], bB[2][2];

  // prologue: stage tiles 0,1,2; publish 0,1; preload frags(0)
  stageA(0); stageB(0); stageA(1); stageB(1); stageA(2); stageB(2);
  asm volatile("s_waitcnt vmcnt(%0)" :: "i"(LPT) : "memory");  // t0,t1 landed
  __builtin_amdgcn_s_barrier();
  readFrags(0, aA, bA);

  auto body = [&](int t, bf16x8 (&aCur)[2][FM], bf16x8 (&bCur)[2][2],
                  bf16x8 (&aNxt)[2][FM], bf16x8 (&bNxt)[2][2]) {
    readFrags(t + 1, aNxt, bNxt);
    if (t + 3 < nt) { stageA(t + 3); stageB(t + 3); }
    mfmaTile(aCur, bCur);
    if (t + 3 < nt) asm volatile("s_waitcnt vmcnt(%0)" :: "i"(LPT) : "memory");
    else            asm volatile("s_waitcnt vmcnt(0)" ::: "memory");
    __builtin_amdgcn_s_barrier();  // publish t+2
  };

  for (int t = 0; t < nt - 2; t += 2) {
    body(t,     aA, bA, aB, bB);
    body(t + 1, aB, bB, aA, bA);
  }
  body(nt - 2, aA, bA, aB, bB);   // reads frags(nt-1); drains staging
  mfmaTile(aB, bB);               // compiler inserts the lgkm wait it needs

  // ---- epilogue: bias + optional ReLU; C: col=lane&31,
  // row=(r&3)+8*(r>>2)+4*kh ----
  float bv[2];
#pragma unroll
  for (int j = 0; j < 2; ++j) bv[j] = bias[col0 + wn * 64 + j * 32 + l31];

  const int rb = row0 + wm * WaveM + 4 * kh;
  const int cb = col0 + wn * 64 + l31;
#pragma unroll
  for (int i = 0; i < FM; ++i) {
#pragma unroll
    for (int j = 0; j < 2; ++j) {
#pragma unroll
      for (int r = 0; r < 16; ++r) {
        float v = acc[i][j][r] + bv[j];
        if (RELU) v = fmaxf(v, 0.0f);
        const int row = rb + i * 32 + (r & 3) + 8 * (r >> 2);
        const size_t idx = (size_t)row * N + (cb + j * 32);
        if (OUTBF16) ((unsigned short*)out)[idx] = f2bf(v);
        else         ((float*)out)[idx] = v;
      }
    }
  }
}

// ---------------------------------------------------------------------------
extern "C" void kernel_launch(void* const* d_in, const int* in_sizes, int n_in,
                              void* d_out, int out_size, void* d_ws, size_t ws_size,
                              hipStream_t stream) {
  const float* x   = (const float*)d_in[0];
  const float* mW0 = (const float*)d_in[1];
  const float* sW0 = (const float*)d_in[2];
  const float* zW0 = (const float*)d_in[3];
  const float* mb0 = (const float*)d_in[4];
  const float* sb0 = (const float*)d_in[5];
  const float* zb0 = (const float*)d_in[6];
  const float* mW1 = (const float*)d_in[7];
  const float* sW1 = (const float*)d_in[8];
  const float* zW1 = (const float*)d_in[9];
  const float* mb1 = (const float*)d_in[10];
  const float* sb1 = (const float*)d_in[11];
  const float* zb1 = (const float*)d_in[12];
  const float* mW2 = (const float*)d_in[13];
  const float* sW2 = (const float*)d_in[14];
  const float* zW2 = (const float*)d_in[15];
  const float* mb2 = (const float*)d_in[16];
  const float* sb2 = (const float*)d_in[17];
  const float* zb2 = (const float*)d_in[18];

  char* ws = (char*)d_ws;
  size_t off = 0;
  auto alloc = [&](size_t bytes) {
    char* p = ws + off;
    off += (bytes + 255) & ~(size_t)255;
    return p;
  };
  unsigned short* xb = (unsigned short*)alloc(8192ull * 1024 * 2);
  unsigned short* A0 = (unsigned short*)alloc(4096ull * 1024 * 2);
  unsigned short* A1 = (unsigned short*)alloc(4096ull * 4096 * 2);
  unsigned short* A2 = (unsigned short*)alloc(1024ull * 4096 * 2);
  unsigned short* h1 = (unsigned short*)alloc(8192ull * 4096 * 2);
  unsigned short* h2 = (unsigned short*)alloc(8192ull * 4096 * 2);
  float* b0 = (float*)alloc(4096 * 4);
  float* b1 = (float*)alloc(4096 * 4);
  float* b2 = (float*)alloc(1024 * 4);

  fuse_w_kernel<<<2048, 256, 0, stream>>>(mW0, sW0, zW0, A0, (4096 * 1024) / 4);
  fuse_w_kernel<<<2048, 256, 0, stream>>>(mW1, sW1, zW1, A1, (4096 * 4096) / 4);
  fuse_w_kernel<<<2048, 256, 0, stream>>>(mW2, sW2, zW2, A2, (1024 * 4096) / 4);
  xconv_kernel<<<2048, 256, 0, stream>>>(x, xb, (8192 * 1024) / 4);
  bias_all_kernel<<<36, 256, 0, stream>>>(mb0, sb0, zb0, mb1, sb1, zb1,
                                          mb2, sb2, zb2, b0, b1, b2);

  // layer 0: [8192,1024] @ [4096,1024]^T -> relu -> h1 bf16   (BN=256, 512 wg)
  gemm_pipe_kernel<4, 1, 1><<<512, 512, 0, stream>>>(xb, A0, b0, h1,
                                                     8192, 4096, 1024, 16);
  // layer 1: [8192,4096] @ [4096,4096]^T -> relu -> h2 bf16   (BN=256, 512 wg)
  gemm_pipe_kernel<4, 1, 1><<<512, 512, 0, stream>>>(h1, A1, b1, h2,
                                                     8192, 4096, 4096, 16);
  // layer 2: [8192,4096] @ [1024,4096]^T -> d_out fp32        (BN=128, 256 wg)
  gemm_pipe_kernel<2, 0, 0><<<256, 512, 0, stream>>>(h2, A2, b2, d_out,
                                                     8192, 1024, 4096, 8);
}

// Round 10
// 520.984 us; speedup vs baseline: 1.0238x; 1.0099x over previous
//
#include <hip/hip_runtime.h>
#include <hip/hip_bf16.h>
#include <stdint.h>

#define DEVFN static __device__ __forceinline__

typedef __bf16 bf16x8 __attribute__((ext_vector_type(8)));
typedef float f32x4 __attribute__((ext_vector_type(4)));

DEVFN unsigned short f2bf(float f) {
  unsigned int u = __float_as_uint(f);
  u += 0x7FFFu + ((u >> 16) & 1u);
  return (unsigned short)(u >> 16);
}

DEVFN float softplus_f(float s) {
  return fmaxf(s, 0.0f) + log1pf(__expf(-fabsf(s)));
}

DEVFN void load_lds16(const void* g, void* l) {
  __builtin_amdgcn_global_load_lds(
      (const __attribute__((address_space(1))) void*)g,
      (__attribute__((address_space(3))) void*)l, 16, 0, 0);
}

// ---------------- elementwise: A = mW + softplus(sW)*zW  (fp32 -> bf16) ----
__global__ void fuse_w_kernel(const float* __restrict__ m, const float* __restrict__ s,
                              const float* __restrict__ z, unsigned short* __restrict__ o,
                              int n4) {
  int stride = gridDim.x * blockDim.x;
  for (int i = blockIdx.x * blockDim.x + threadIdx.x; i < n4; i += stride) {
    float4 mv = reinterpret_cast<const float4*>(m)[i];
    float4 sv = reinterpret_cast<const float4*>(s)[i];
    float4 zv = reinterpret_cast<const float4*>(z)[i];
    ushort4 ov;
    ov.x = f2bf(fmaf(softplus_f(sv.x), zv.x, mv.x));
    ov.y = f2bf(fmaf(softplus_f(sv.y), zv.y, mv.y));
    ov.z = f2bf(fmaf(softplus_f(sv.z), zv.z, mv.z));
    ov.w = f2bf(fmaf(softplus_f(sv.w), zv.w, mv.w));
    reinterpret_cast<ushort4*>(o)[i] = ov;
  }
}

// ---------------- all three biases in one launch ---------------------------
__global__ void bias_all_kernel(const float* __restrict__ mb0, const float* __restrict__ sb0,
                                const float* __restrict__ zb0,
                                const float* __restrict__ mb1, const float* __restrict__ sb1,
                                const float* __restrict__ zb1,
                                const float* __restrict__ mb2, const float* __restrict__ sb2,
                                const float* __restrict__ zb2,
                                float* __restrict__ b0, float* __restrict__ b1,
                                float* __restrict__ b2) {
  int i = blockIdx.x * blockDim.x + threadIdx.x;
  if (i < 4096) {
    b0[i] = fmaf(softplus_f(sb0[i]), zb0[i], mb0[i]);
  } else if (i < 8192) {
    int k = i - 4096;
    b1[k] = fmaf(softplus_f(sb1[k]), zb1[k], mb1[k]);
  } else if (i < 9216) {
    int k = i - 8192;
    b2[k] = fmaf(softplus_f(sb2[k]), zb2[k], mb2[k]);
  }
}

// ---------------- x fp32 -> bf16 -------------------------------------------
__global__ void xconv_kernel(const float* __restrict__ x, unsigned short* __restrict__ o,
                             int n4) {
  int stride = gridDim.x * blockDim.x;
  for (int i = blockIdx.x * blockDim.x + threadIdx.x; i < n4; i += stride) {
    float4 v = reinterpret_cast<const float4*>(x)[i];
    ushort4 ov;
    ov.x = f2bf(v.x); ov.y = f2bf(v.y); ov.z = f2bf(v.z); ov.w = f2bf(v.w);
    reinterpret_cast<ushort4*>(o)[i] = ov;
  }
}

// ===========================================================================
// R10: occupancy-first GEMM. Tile (WM*64) x (WN*64), WM*WN waves, each wave
// owns a 64x64 output tile (acc = 16 x f32x4 = 64 VGPR). 16x16x32 MFMA
// (the shape whose LDS read pattern measured ZERO bank conflicts, R4-R7;
// the 32x32 experiment measured 2.5e7 regardless of swizzle -> closed).
//
// __launch_bounds__(threads, 4): 4 waves/SIMD resident => cross-wave
// overlap (m114 mechanism) hides the per-wave serial {ds_read -> MFMA}
// chain that pinned R4-R9's 1-block/CU configs at 46-53% MfmaUtil.
// G0/G1: 256x128, 8 waves, ring-2 LDS = 48KB -> 2 blocks/CU (VGPR-capped).
// G2:    128x128, 4 waves, ring-2 LDS = 32KB -> 4 blocks/CU.
//
// Ring-2 loop (m97-style, race-free by slot parity):
//   iter t: readFrags(slot t&1); stage(t+1 -> slot (t+1)&1); MFMA(t);
//           vmcnt(0) [covered by the MFMA cluster + the other block];
//           s_barrier [publishes t+1; also fences: all waves' reads of
//           slot t&1 completed (MFMA consumed them) before iter t+1's
//           stage(t+2) overwrites it].
//
// T2 swizzle (verified 0 conflicts R4-R7): stage pre-swizzles the per-lane
// GLOBAL source 16B-chunk (cc ^= (row>>1)&3; LDS dest linear, rule 21);
// fragment reads use kg ^ ((l15>>1)&3) (lane-constant). Row steps of A/B
// staging loads are multiples of 64 -> swizzle-invariant.
// T1 bijective XCD swizzle on a 1-D grid (all grids % 8 == 0).
// ===========================================================================
template <int WM, int WN, int RELU, int OUTBF16>
__global__ __launch_bounds__(WM * WN * 64, 4) void gemm_occ_kernel(
    const unsigned short* __restrict__ X, const unsigned short* __restrict__ W,
    const float* __restrict__ bias, void* __restrict__ out,
    int M, int N, int K, int gx) {
  constexpr int NT  = WM * WN * 64;     // threads
  constexpr int BM  = WM * 64;
  constexpr int BN  = WN * 64;
  constexpr int ASZ = BM * 64;          // A slot bytes (BM rows x 64B)
  constexpr int BSZ = BN * 64;
  constexpr int ALD = 4 / WN;           // A gloads per thread per tile
  constexpr int BLD = 4 / WM;           // B gloads per thread per tile
  __shared__ __align__(16) char lds[2 * (ASZ + BSZ)];

  // T1: bijective XCD swizzle (grid % 8 == 0 for all launches here)
  const int nwg = gridDim.x;
  const int bid = blockIdx.x;
  const int nid = (bid & 7) * (nwg >> 3) + (bid >> 3);
  const int bx  = nid % gx;
  const int by  = nid / gx;

  const int tid  = threadIdx.x;
  const int lane = tid & 63;
  const int wv   = tid >> 6;
  const int wm   = wv / WN;
  const int wn   = wv % WN;
  const int row0 = by * BM;
  const int col0 = bx * BN;
  const size_t ldb = (size_t)K * 2;

  // staging: chunk c -> row c>>2, chunkcol c&3; source chunkcol pre-swizzled
  const int rS  = tid >> 2;
  const int ccS = (tid & 3) ^ ((rS >> 1) & 3);
  const char* srcA = (const char*)X + (size_t)(row0 + rS) * ldb + ccS * 16;
  const char* srcB = (const char*)W + (size_t)(col0 + rS) * ldb + ccS * 16;

  auto stage = [&](int tt) {
    char* dA = lds + (tt & 1) * ASZ;
    char* dB = lds + 2 * ASZ + (tt & 1) * BSZ;
    const size_t kb = (size_t)tt * 64;
#pragma unroll
    for (int l = 0; l < ALD; ++l)   // row step NT/4 (mult of 64): swz-invariant
      load_lds16(srcA + kb + (size_t)l * (NT / 4) * ldb, dA + tid * 16 + l * NT * 16);
#pragma unroll
    for (int l = 0; l < BLD; ++l)
      load_lds16(srcB + kb + (size_t)l * (NT / 4) * ldb, dB + tid * 16 + l * NT * 16);
  };

  // fragment byte offsets (proven conflict-free 16x16 pattern)
  const int l15 = lane & 15;
  const int kg  = lane >> 4;
  const int kgs = kg ^ ((l15 >> 1) & 3);
  int aOff[4], bOff[4];
#pragma unroll
  for (int i = 0; i < 4; ++i)
    aOff[i] = (wm * 64 + i * 16 + l15) * 64 + kgs * 16;
#pragma unroll
  for (int j = 0; j < 4; ++j)
    bOff[j] = (wn * 64 + j * 16 + l15) * 64 + kgs * 16;

  f32x4 acc[4][4];
#pragma unroll
  for (int i = 0; i < 4; ++i)
#pragma unroll
    for (int j = 0; j < 4; ++j)
      acc[i][j] = (f32x4){0.f, 0.f, 0.f, 0.f};

  const int nt = K >> 5;

  // prologue: stage tile 0, publish
  stage(0);
  asm volatile("s_waitcnt vmcnt(0)" ::: "memory");
  __builtin_amdgcn_s_barrier();

  for (int t = 0; t < nt; ++t) {
    const char* sa = lds + (t & 1) * ASZ;
    const char* sb = lds + 2 * ASZ + (t & 1) * BSZ;
    bf16x8 aF[4], bF[4];
#pragma unroll
    for (int i = 0; i < 4; ++i) aF[i] = *(const bf16x8*)(sa + aOff[i]);
#pragma unroll
    for (int j = 0; j < 4; ++j) bF[j] = *(const bf16x8*)(sb + bOff[j]);

    if (t + 1 < nt) stage(t + 1);   // opposite slot: never the one being read

    __builtin_amdgcn_s_setprio(1);
#pragma unroll
    for (int i = 0; i < 4; ++i)
#pragma unroll
      for (int j = 0; j < 4; ++j)
        acc[i][j] = __builtin_amdgcn_mfma_f32_16x16x32_bf16(aF[i], bF[j], acc[i][j], 0, 0, 0);
    __builtin_amdgcn_s_setprio(0);

    if (t + 1 < nt) asm volatile("s_waitcnt vmcnt(0)" ::: "memory");
    __builtin_amdgcn_s_barrier();
  }

  // ---- epilogue: bias + optional ReLU; C: col=lane&15, row=kg*4+r ----
  float bv[4];
#pragma unroll
  for (int j = 0; j < 4; ++j) bv[j] = bias[col0 + wn * 64 + j * 16 + l15];

  const int rbase = row0 + wm * 64 + kg * 4;
  const int cbase = col0 + wn * 64 + l15;
#pragma unroll
  for (int i = 0; i < 4; ++i) {
#pragma unroll
    for (int j = 0; j < 4; ++j) {
#pragma unroll
      for (int r = 0; r < 4; ++r) {
        float v = acc[i][j][r] + bv[j];
        if (RELU) v = fmaxf(v, 0.0f);
        const size_t idx = (size_t)(rbase + i * 16 + r) * N + (cbase + j * 16);
        if (OUTBF16) ((unsigned short*)out)[idx] = f2bf(v);
        else         ((float*)out)[idx] = v;
      }
    }
  }
}

// ---------------------------------------------------------------------------
extern "C" void kernel_launch(void* const* d_in, const int* in_sizes, int n_in,
                              void* d_out, int out_size, void* d_ws, size_t ws_size,
                              hipStream_t stream) {
  const float* x   = (const float*)d_in[0];
  const float* mW0 = (const float*)d_in[1];
  const float* sW0 = (const float*)d_in[2];
  const float* zW0 = (const float*)d_in[3];
  const float* mb0 = (const float*)d_in[4];
  const float* sb0 = (const float*)d_in[5];
  const float* zb0 = (const float*)d_in[6];
  const float* mW1 = (const float*)d_in[7];
  const float* sW1 = (const float*)d_in[8];
  const float* zW1 = (const float*)d_in[9];
  const float* mb1 = (const float*)d_in[10];
  const float* sb1 = (const float*)d_in[11];
  const float* zb1 = (const float*)d_in[12];
  const float* mW2 = (const float*)d_in[13];
  const float* sW2 = (const float*)d_in[14];
  const float* zW2 = (const float*)d_in[15];
  const float* mb2 = (const float*)d_in[16];
  const float* sb2 = (const float*)d_in[17];
  const float* zb2 = (const float*)d_in[18];

  char* ws = (char*)d_ws;
  size_t off = 0;
  auto alloc = [&](size_t bytes) {
    char* p = ws + off;
    off += (bytes + 255) & ~(size_t)255;
    return p;
  };
  unsigned short* xb = (unsigned short*)alloc(8192ull * 1024 * 2);
  unsigned short* A0 = (unsigned short*)alloc(4096ull * 1024 * 2);
  unsigned short* A1 = (unsigned short*)alloc(4096ull * 4096 * 2);
  unsigned short* A2 = (unsigned short*)alloc(1024ull * 4096 * 2);
  unsigned short* h1 = (unsigned short*)alloc(8192ull * 4096 * 2);
  unsigned short* h2 = (unsigned short*)alloc(8192ull * 4096 * 2);
  float* b0 = (float*)alloc(4096 * 4);
  float* b1 = (float*)alloc(4096 * 4);
  float* b2 = (float*)alloc(1024 * 4);

  fuse_w_kernel<<<2048, 256, 0, stream>>>(mW0, sW0, zW0, A0, (4096 * 1024) / 4);
  fuse_w_kernel<<<2048, 256, 0, stream>>>(mW1, sW1, zW1, A1, (4096 * 4096) / 4);
  fuse_w_kernel<<<2048, 256, 0, stream>>>(mW2, sW2, zW2, A2, (1024 * 4096) / 4);
  xconv_kernel<<<2048, 256, 0, stream>>>(x, xb, (8192 * 1024) / 4);
  bias_all_kernel<<<36, 256, 0, stream>>>(mb0, sb0, zb0, mb1, sb1, zb1,
                                          mb2, sb2, zb2, b0, b1, b2);

  // layer 0: [8192,1024]@[4096,1024]^T -> relu -> h1   (256x128, 1024 wg)
  gemm_occ_kernel<4, 2, 1, 1><<<1024, 512, 0, stream>>>(xb, A0, b0, h1,
                                                        8192, 4096, 1024, 32);
  // layer 1: [8192,4096]@[4096,4096]^T -> relu -> h2   (256x128, 1024 wg)
  gemm_occ_kernel<4, 2, 1, 1><<<1024, 512, 0, stream>>>(h1, A1, b1, h2,
                                                        8192, 4096, 4096, 32);
  // layer 2: [8192,4096]@[1024,4096]^T -> d_out fp32   (128x128, 512 wg)
  gemm_occ_kernel<2, 2, 0, 0><<<512, 256, 0, stream>>>(h2, A2, b2, d_out,
                                                       8192, 1024, 4096, 8);
}

// Round 11
// 484.316 us; speedup vs baseline: 1.1013x; 1.0757x over previous
//
#include <hip/hip_runtime.h>
#include <hip/hip_bf16.h>
#include <stdint.h>

#define DEVFN static __device__ __forceinline__

typedef __bf16 bf16x8 __attribute__((ext_vector_type(8)));
typedef float f32x4 __attribute__((ext_vector_type(4)));

DEVFN unsigned short f2bf(float f) {
  unsigned int u = __float_as_uint(f);
  u += 0x7FFFu + ((u >> 16) & 1u);
  return (unsigned short)(u >> 16);
}

DEVFN float softplus_f(float s) {
  return fmaxf(s, 0.0f) + log1pf(__expf(-fabsf(s)));
}

DEVFN void load_lds16(const void* g, void* l) {
  __builtin_amdgcn_global_load_lds(
      (const __attribute__((address_space(1))) void*)g,
      (__attribute__((address_space(3))) void*)l, 16, 0, 0);
}

// ---------------- fused prep: all weight fuses + x conv + biases -----------
// One grid-stride launch over a virtual float4 index space:
//   [0,N0)        W0 fuse -> A0 bf16
//   [N0,N0+N1)    W1 fuse -> A1
//   [..+N2)       W2 fuse -> A2
//   [..+N3)       x fp32 -> bf16
//   [..+N4)       biases (4 scalars per slot)
DEVFN void fuse4(const float* __restrict__ m, const float* __restrict__ s,
                 const float* __restrict__ z, unsigned short* __restrict__ o, int i) {
  float4 mv = reinterpret_cast<const float4*>(m)[i];
  float4 sv = reinterpret_cast<const float4*>(s)[i];
  float4 zv = reinterpret_cast<const float4*>(z)[i];
  ushort4 ov;
  ov.x = f2bf(fmaf(softplus_f(sv.x), zv.x, mv.x));
  ov.y = f2bf(fmaf(softplus_f(sv.y), zv.y, mv.y));
  ov.z = f2bf(fmaf(softplus_f(sv.z), zv.z, mv.z));
  ov.w = f2bf(fmaf(softplus_f(sv.w), zv.w, mv.w));
  reinterpret_cast<ushort4*>(o)[i] = ov;
}

__global__ void prep_kernel(const float* __restrict__ mW0, const float* __restrict__ sW0,
                            const float* __restrict__ zW0,
                            const float* __restrict__ mW1, const float* __restrict__ sW1,
                            const float* __restrict__ zW1,
                            const float* __restrict__ mW2, const float* __restrict__ sW2,
                            const float* __restrict__ zW2,
                            const float* __restrict__ x,
                            const float* __restrict__ mb0, const float* __restrict__ sb0,
                            const float* __restrict__ zb0,
                            const float* __restrict__ mb1, const float* __restrict__ sb1,
                            const float* __restrict__ zb1,
                            const float* __restrict__ mb2, const float* __restrict__ sb2,
                            const float* __restrict__ zb2,
                            unsigned short* __restrict__ A0, unsigned short* __restrict__ A1,
                            unsigned short* __restrict__ A2, unsigned short* __restrict__ xb,
                            float* __restrict__ b0, float* __restrict__ b1,
                            float* __restrict__ b2) {
  const int N0 = 1048576;            // 4096*1024/4
  const int N1 = 4194304;            // 4096*4096/4
  const int N2 = 1048576;            // 1024*4096/4
  const int N3 = 2097152;            // 8192*1024/4
  const int N4 = 2304;               // 9216 bias scalars / 4
  const int NT = N0 + N1 + N2 + N3 + N4;
  int stride = gridDim.x * blockDim.x;
  for (int i = blockIdx.x * blockDim.x + threadIdx.x; i < NT; i += stride) {
    if (i < N0) {
      fuse4(mW0, sW0, zW0, A0, i);
    } else if (i < N0 + N1) {
      fuse4(mW1, sW1, zW1, A1, i - N0);
    } else if (i < N0 + N1 + N2) {
      fuse4(mW2, sW2, zW2, A2, i - N0 - N1);
    } else if (i < N0 + N1 + N2 + N3) {
      int k = i - N0 - N1 - N2;
      float4 v = reinterpret_cast<const float4*>(x)[k];
      ushort4 ov;
      ov.x = f2bf(v.x); ov.y = f2bf(v.y); ov.z = f2bf(v.z); ov.w = f2bf(v.w);
      reinterpret_cast<ushort4*>(xb)[k] = ov;
    } else {
      int k = (i - N0 - N1 - N2 - N3) * 4;
#pragma unroll
      for (int u = 0; u < 4; ++u) {
        int e = k + u;
        if (e < 4096)      b0[e]        = fmaf(softplus_f(sb0[e]),        zb0[e],        mb0[e]);
        else if (e < 8192) b1[e - 4096] = fmaf(softplus_f(sb1[e - 4096]), zb1[e - 4096], mb1[e - 4096]);
        else               b2[e - 8192] = fmaf(softplus_f(sb2[e - 8192]), zb2[e - 8192], mb2[e - 8192]);
      }
    }
  }
}

// ===========================================================================
// Pipelined GEMM (R7 config — measured best: G1 239.6us, MfmaUtil 52.8,
// bank conflicts 0). BM=256, BK=32, BN = WN*64 (WN=4 -> 256, WN=2 -> 128).
// 8 waves as (8/WN) M-rows x WN N-cols. 16x16x32 MFMA.
//
// R11 tweak: stage(t+3) issued BEFORE readFrags(t+1) (T3 recipe order —
// global loads get max latency slack). Ring/ledger unchanged: stage slot
// (t+3)&3 vs read slot (t+1)&3 disjoint; vmcnt(LPT) at tile end leaves
// only stage(t+3) in flight => t+2 landed; barrier publishes.
//
// No lgkm pins / sched_barriers: compiler emits fine-grained counted
// lgkmcnt for frag->MFMA deps (R7 validation: pins are neutral-to-harmful).
// T2 swizzle (verified 0 conflicts): stage pre-swizzles per-lane GLOBAL
// source 16B-chunk (cc ^= (row>>1)&3, LDS dest linear); read kg^((l15>>1)&3).
// T1 bijective XCD swizzle (grids % 8 == 0).
// ===========================================================================
template <int WN, int RELU, int OUTBF16>
__global__ __launch_bounds__(512, 2) void gemm_pipe_kernel(
    const unsigned short* __restrict__ X, const unsigned short* __restrict__ W,
    const float* __restrict__ bias, void* __restrict__ out,
    int M, int N, int K, int gx) {
  constexpr int BN  = WN * 64;         // 256 or 128
  constexpr int MF  = 2 * WN;          // A-frags per wave (8 or 4)
  constexpr int LPT = (WN == 4) ? 4 : 3;  // global_load_lds per tile per thread
  constexpr int BS  = BN * 32;         // B slot size, ushorts
  __shared__ __align__(16) unsigned short lds[32768 + 4 * BS];

  const int nwg = gridDim.x;
  const int bid = blockIdx.x;
  const int nid = (bid & 7) * (nwg >> 3) + (bid >> 3);
  const int bx  = nid % gx;
  const int by  = nid / gx;

  const int tid  = threadIdx.x;
  const int lane = tid & 63;
  const int wv   = tid >> 6;                 // 0..7
  const int wm   = wv / WN;
  const int wn   = wv % WN;
  const int row0 = by * 256;
  const int col0 = bx * BN;
  const size_t ldb = (size_t)K * 2;

  const int cA  = wv * 64 + lane;
  const int rS  = cA >> 2;
  const int ccS = (cA & 3) ^ ((rS >> 1) & 3);
  const char* srcA = (const char*)X + (size_t)(row0 + rS) * ldb + ccS * 16;
  const char* srcB = (const char*)W + (size_t)(col0 + rS) * ldb + ccS * 16;
  char* ldsb = (char*)lds;

  auto stageA = [&](int tt) {
    char* d = ldsb + (tt & 3) * 16384 + wv * 1024;
    const char* s = srcA + (size_t)tt * 64;
    load_lds16(s, d);
    load_lds16(s + 128 * ldb, d + 8192);     // rows +128: swizzle invariant
  };
  auto stageB = [&](int tt) {
    char* d = ldsb + 65536 + (tt & 3) * (BS * 2) + wv * 1024;
    const char* s = srcB + (size_t)tt * 64;
    load_lds16(s, d);
    if constexpr (WN == 4) load_lds16(s + 128 * ldb, d + 8192);
  };

  const int l15 = lane & 15;
  const int kg  = lane >> 4;
  const int kgs = kg ^ ((l15 >> 1) & 3);
  const int aIdx = (wm * (32 * WN) + l15) * 32 + kgs * 8;
  const int bIdx = (wn * 64 + l15) * 32 + kgs * 8;

  f32x4 acc[MF][4];
#pragma unroll
  for (int i = 0; i < MF; ++i)
#pragma unroll
    for (int j = 0; j < 4; ++j)
      acc[i][j] = (f32x4){0.f, 0.f, 0.f, 0.f};

  auto readFrags = [&](int tt, bf16x8 (&aF)[MF], bf16x8 (&bF)[4]) {
    const int sa = (tt & 3) * 8192;
    const int sb = 32768 + (tt & 3) * BS;
#pragma unroll
    for (int i = 0; i < MF; ++i) aF[i] = *(const bf16x8*)&lds[sa + aIdx + i * 512];
#pragma unroll
    for (int j = 0; j < 4; ++j)  bF[j] = *(const bf16x8*)&lds[sb + bIdx + j * 512];
  };
  auto mfmaTile = [&](bf16x8 (&aF)[MF], bf16x8 (&bF)[4]) {
    __builtin_amdgcn_s_setprio(1);
#pragma unroll
    for (int i = 0; i < MF; ++i)
#pragma unroll
      for (int j = 0; j < 4; ++j)
        acc[i][j] = __builtin_amdgcn_mfma_f32_16x16x32_bf16(aF[i], bF[j], acc[i][j], 0, 0, 0);
    __builtin_amdgcn_s_setprio(0);
  };

  const int nt = K >> 5;
  bf16x8 aA[MF], bA[4], aB[MF], bB[4];

  // prologue: stage tiles 0,1,2; publish 0,1; preload frags(0)
  stageA(0); stageB(0); stageA(1); stageB(1); stageA(2); stageB(2);
  asm volatile("s_waitcnt vmcnt(%0)" :: "i"(LPT) : "memory");  // t0,t1 landed
  __builtin_amdgcn_s_barrier();
  readFrags(0, aA, bA);

  auto body = [&](int t, bf16x8 (&aCur)[MF], bf16x8 (&bCur)[4],
                  bf16x8 (&aNxt)[MF], bf16x8 (&bNxt)[4]) {
    if (t + 3 < nt) { stageA(t + 3); stageB(t + 3); }   // issue earliest
    readFrags(t + 1, aNxt, bNxt);
    mfmaTile(aCur, bCur);
    if (t + 3 < nt) asm volatile("s_waitcnt vmcnt(%0)" :: "i"(LPT) : "memory");
    else            asm volatile("s_waitcnt vmcnt(0)" ::: "memory");
    __builtin_amdgcn_s_barrier();  // publish t+2
  };

  for (int t = 0; t < nt - 2; t += 2) {
    body(t,     aA, bA, aB, bB);
    body(t + 1, aB, bB, aA, bA);
  }
  body(nt - 2, aA, bA, aB, bB);   // reads frags(nt-1); drains staging
  mfmaTile(aB, bB);               // compiler inserts the lgkm wait it needs

  // ---- epilogue: bias + optional ReLU ----
  float bv[4];
#pragma unroll
  for (int j = 0; j < 4; ++j) bv[j] = bias[col0 + wn * 64 + j * 16 + l15];

  const int rbase = row0 + wm * (32 * WN) + kg * 4;
  const int cbase = col0 + wn * 64 + l15;
#pragma unroll
  for (int i = 0; i < MF; ++i) {
#pragma unroll
    for (int j = 0; j < 4; ++j) {
#pragma unroll
      for (int r = 0; r < 4; ++r) {
        float v = acc[i][j][r] + bv[j];
        if (RELU) v = fmaxf(v, 0.0f);
        const size_t idx = (size_t)(rbase + i * 16 + r) * N + (cbase + j * 16);
        if (OUTBF16) ((unsigned short*)out)[idx] = f2bf(v);
        else         ((float*)out)[idx] = v;
      }
    }
  }
}

// ---------------------------------------------------------------------------
extern "C" void kernel_launch(void* const* d_in, const int* in_sizes, int n_in,
                              void* d_out, int out_size, void* d_ws, size_t ws_size,
                              hipStream_t stream) {
  const float* x   = (const float*)d_in[0];
  const float* mW0 = (const float*)d_in[1];
  const float* sW0 = (const float*)d_in[2];
  const float* zW0 = (const float*)d_in[3];
  const float* mb0 = (const float*)d_in[4];
  const float* sb0 = (const float*)d_in[5];
  const float* zb0 = (const float*)d_in[6];
  const float* mW1 = (const float*)d_in[7];
  const float* sW1 = (const float*)d_in[8];
  const float* zW1 = (const float*)d_in[9];
  const float* mb1 = (const float*)d_in[10];
  const float* sb1 = (const float*)d_in[11];
  const float* zb1 = (const float*)d_in[12];
  const float* mW2 = (const float*)d_in[13];
  const float* sW2 = (const float*)d_in[14];
  const float* zW2 = (const float*)d_in[15];
  const float* mb2 = (const float*)d_in[16];
  const float* sb2 = (const float*)d_in[17];
  const float* zb2 = (const float*)d_in[18];

  char* ws = (char*)d_ws;
  size_t off = 0;
  auto alloc = [&](size_t bytes) {
    char* p = ws + off;
    off += (bytes + 255) & ~(size_t)255;
    return p;
  };
  unsigned short* xb = (unsigned short*)alloc(8192ull * 1024 * 2);
  unsigned short* A0 = (unsigned short*)alloc(4096ull * 1024 * 2);
  unsigned short* A1 = (unsigned short*)alloc(4096ull * 4096 * 2);
  unsigned short* A2 = (unsigned short*)alloc(1024ull * 4096 * 2);
  unsigned short* h1 = (unsigned short*)alloc(8192ull * 4096 * 2);
  unsigned short* h2 = (unsigned short*)alloc(8192ull * 4096 * 2);
  float* b0 = (float*)alloc(4096 * 4);
  float* b1 = (float*)alloc(4096 * 4);
  float* b2 = (float*)alloc(1024 * 4);

  prep_kernel<<<2048, 256, 0, stream>>>(mW0, sW0, zW0, mW1, sW1, zW1,
                                        mW2, sW2, zW2, x,
                                        mb0, sb0, zb0, mb1, sb1, zb1,
                                        mb2, sb2, zb2,
                                        A0, A1, A2, xb, b0, b1, b2);

  // layer 0: [8192,1024] @ [4096,1024]^T -> relu -> h1 bf16   (BN=256, 512 wg)
  gemm_pipe_kernel<4, 1, 1><<<512, 512, 0, stream>>>(xb, A0, b0, h1,
                                                     8192, 4096, 1024, 16);
  // layer 1: [8192,4096] @ [4096,4096]^T -> relu -> h2 bf16   (BN=256, 512 wg)
  gemm_pipe_kernel<4, 1, 1><<<512, 512, 0, stream>>>(h1, A1, b1, h2,
                                                     8192, 4096, 4096, 16);
  // layer 2: [8192,4096] @ [1024,4096]^T -> d_out fp32        (BN=128, 256 wg)
  gemm_pipe_kernel<2, 0, 0><<<256, 512, 0, stream>>>(h2, A2, b2, d_out,
                                                     8192, 1024, 4096, 8);
}